// Round 8
// baseline (110.315 us; speedup 1.0000x reference)
//
#include <hip/hip_runtime.h>
#include <math.h>

#define N_B 16
#define C_CH 128
#define T_LEN 513
#define NI 257
#define NJ 256
#define SCALE (1.4426950408889634f/128.0f)     // log2(e)/C

typedef unsigned u32;
typedef unsigned short u16;
typedef short bf16x8 __attribute__((ext_vector_type(8)));
typedef float f32x4 __attribute__((ext_vector_type(4)));

// workspace: RAM f32[16][257][256] @0 ; pda f32[16][17][256] ; barrier counter
#define RAM_F 0
#define PDA_F (N_B*NI*NJ)                       // 1,052,672
#define CNT_BYTE ((PDA_F + N_B*17*NJ) * 4)      // 4,489,216

__device__ inline u16 bf16_rne(float f) {
    const u32 u = __builtin_bit_cast(u32, f);
    return (u16)((u + 0x7fffu + ((u >> 16) & 1u)) >> 16);
}

__device__ inline void cvt8(float4 f0, float4 f1, bf16x8& hv, bf16x8& lv) {
    const float fs[8] = {f0.x, f0.y, f0.z, f0.w, f1.x, f1.y, f1.z, f1.w};
    union { u32 w[4]; bf16x8 v; } H, L;
    #pragma unroll
    for (int p = 0; p < 4; ++p) {
        const float a = fs[2*p], b = fs[2*p+1];
        const u16 ha = bf16_rne(a), hb = bf16_rne(b);
        const float ra = a - __builtin_bit_cast(float, (u32)ha << 16);
        const float rb = b - __builtin_bit_cast(float, (u32)hb << 16);
        const u16 la = bf16_rne(ra), lb = bf16_rne(rb);
        H.w[p] = (u32)ha | ((u32)hb << 16);
        L.w[p] = (u32)la | ((u32)lb << 16);
    }
    hv = H.v; lv = L.v;
}

__device__ inline float dot8(float4 a, float4 b) {
    return a.x*a.x + a.y*a.y + a.z*a.z + a.w*a.w
         + b.x*b.x + b.y*b.y + b.z*b.z + b.w*b.w;
}

__global__ __launch_bounds__(1024, 4) void k_all(const float* __restrict__ x,
                                                 float* __restrict__ ws,
                                                 float* __restrict__ out) {
    __shared__ float smem[35904];                 // 143,616 B <= 160 KiB
    float (*Ar)[132] = (float (*)[132])smem;            // [16][132]
    float (*Br)[132] = (float (*)[132])(smem + 16*132); // [256][132]
    float* ram = ws + RAM_F;
    float* pda = ws + PDA_F;
    u32* cnt = (u32*)((char*)ws + CNT_BYTE);

    const int tid = threadIdx.x, bid = blockIdx.x;
    const int l = tid & 63, wv = tid >> 6, il = l & 15, g = (l >> 4) & 3;

    // ================= Phase 1: RAM + pda (unit = (n, ib), 272 units) =================
    for (int u = bid; u < 272; u += 256) {
        const int n = u / 17, ib = u % 17, i0 = ib * 16;
        const float* xn = x + (size_t)n * (C_CH * T_LEN);
        __syncthreads();                          // smem reuse across iterations
        {   // stage A: even t rows i0..i0+15 (zero-pad i>256)
            const int r = tid & 15, cb = tid >> 4;          // cb 0..63
            #pragma unroll
            for (int p = 0; p < 2; ++p) {
                const int c = cb + 64 * p;
                const int i = i0 + r;
                float v = 0.f;
                if (i < 256)       v = xn[c * T_LEN + 2 * i];
                else if (i == 256) v = xn[c * T_LEN + 512];
                Ar[r][c] = v;
            }
        }
        {   // stage B: odd t, all j (float2 covers {even,odd}, keep odd)
            const int uu = tid & 63, w8 = tid >> 6;
            #pragma unroll
            for (int p = 0; p < 8; ++p) {
                const int c = w8 + 16 * p;
                #pragma unroll
                for (int s = 0; s < 4; ++s) {
                    const int j = uu + 64 * s;
                    const float2 v = *(const float2*)&xn[c * T_LEN + 2 * j];
                    Br[j][c] = v.y;
                }
            }
        }
        __syncthreads();

        bf16x8 ah[4], alo[4], bh[4], blo[4];
        float psum = 0.f, qsq = 0.f;
        #pragma unroll
        for (int kc = 0; kc < 4; ++kc) {
            const float* ap = &Ar[il][32 * kc + 8 * g];
            const float4 a0 = *(const float4*)ap, a1 = *(const float4*)(ap + 4);
            psum += dot8(a0, a1);
            cvt8(a0, a1, ah[kc], alo[kc]);
            const float* bp = &Br[16 * wv + il][32 * kc + 8 * g];
            const float4 b0 = *(const float4*)bp, b1 = *(const float4*)(bp + 4);
            qsq += dot8(b0, b1);
            cvt8(b0, b1, bh[kc], blo[kc]);
        }
        psum += __shfl_xor(psum, 16, 64);
        psum += __shfl_xor(psum, 32, 64);         // P[row il] replicated
        qsq  += __shfl_xor(qsq, 16, 64);
        qsq  += __shfl_xor(qsq, 32, 64);          // Q[col il] replicated
        float pv[4];
        #pragma unroll
        for (int r = 0; r < 4; ++r) pv[r] = __shfl(psum, 4 * g + r, 64);

        f32x4 acc = {0.f, 0.f, 0.f, 0.f};
        #pragma unroll
        for (int kc = 0; kc < 4; ++kc) {
            acc = __builtin_amdgcn_mfma_f32_16x16x32_bf16(ah[kc],  bh[kc],  acc, 0, 0, 0);
            acc = __builtin_amdgcn_mfma_f32_16x16x32_bf16(ah[kc],  blo[kc], acc, 0, 0, 0);
            acc = __builtin_amdgcn_mfma_f32_16x16x32_bf16(alo[kc], bh[kc],  acc, 0, 0, 0);
        }
        float cs = 0.f;
        float* rn = ram + (size_t)n * NI * NJ;
        #pragma unroll
        for (int r = 0; r < 4; ++r) {
            const int i = i0 + 4 * g + r;
            const float rv = exp2f((pv[r] + qsq - 2.f * acc[r]) * SCALE);
            if (i < NI) { rn[(size_t)i * NJ + 16 * wv + il] = rv; cs += rv; }
        }
        cs += __shfl_xor(cs, 16, 64);
        cs += __shfl_xor(cs, 32, 64);
        if (l < 16) pda[((size_t)n * 17 + ib) * NJ + 16 * wv + l] = cs;
    }

    // ================= device-scope grid barrier (counter memset by host per launch) ====
    __syncthreads();
    if (tid == 0) {
        __threadfence();                          // release: flush block's writes
        atomicAdd(cnt, 1u);
        int guard = 0;
        while (atomicAdd(cnt, 0u) < 256u && guard < (1 << 22)) {
            __builtin_amdgcn_s_sleep(8);
            ++guard;
        }
    }
    __syncthreads();
    __threadfence();                              // acquire: invalidate before reads

    // ================= Phase 2: w=rsqrt(da); row reduce; fused apply ==================
    for (int u = bid; u < 272; u += 256) {
        const int n = u / 17, ic = u % 17;
        const float* xn = x + (size_t)n * (C_CH * T_LEN);
        float* on = out + (size_t)n * (C_CH * T_LEN);
        const float* rn = ram + (size_t)n * NI * NJ;
        __syncthreads();                          // smem reuse
        if (tid < NJ) {
            float da = 0.f;
            #pragma unroll
            for (int k = 0; k < 17; ++k) da += pda[((size_t)n * 17 + k) * NJ + tid];
            smem[tid] = rsqrtf(da);               // da >= 257, eps negligible
        }
        __syncthreads();
        {   // one wave per row
            const int i = ic * 16 + wv;
            if (i < NI) {
                const float4 v4 = *(const float4*)&rn[(size_t)i * NJ + 4 * l];
                const float4 w4 = *(const float4*)&smem[4 * l];
                float t0 = v4.x * w4.x + v4.y * w4.y + v4.z * w4.z + v4.w * w4.w;
                float db = v4.x + v4.y + v4.z + v4.w;
                #pragma unroll
                for (int off = 32; off; off >>= 1) {
                    t0 += __shfl_xor(t0, off, 64);
                    db += __shfl_xor(db, off, 64);
                }
                if (l == 0) smem[NJ + wv] = 2.f * t0 * rsqrtf(db);
            }
        }
        __syncthreads();
        {   // apply for t-strip [32*ic, 32*ic+32)
            const int tt = tid & 31, cb = tid >> 5;         // cb 0..31
            const int t = ic * 32 + tt;
            if (t < T_LEN) {
                const float f = smem[NJ + (tt >> 1)];
                #pragma unroll
                for (int p = 0; p < 4; ++p) {
                    const int c = cb + 32 * p;
                    on[(size_t)c * T_LEN + t] = xn[(size_t)c * T_LEN + t] * f;
                }
            }
        }
    }
}

extern "C" void kernel_launch(void* const* d_in, const int* in_sizes, int n_in,
                              void* d_out, int out_size, void* d_ws, size_t ws_size,
                              hipStream_t stream) {
    const float* x = (const float*)d_in[0];
    float* out = (float*)d_out;
    float* ws = (float*)d_ws;
    hipMemsetAsync((char*)d_ws + CNT_BYTE, 0, 64, stream);   // reset barrier counter
    k_all<<<256, 1024, 0, stream>>>(x, ws, out);
}